// Round 2
// baseline (67.073 us; speedup 1.0000x reference)
//
#include <hip/hip_runtime.h>
#include <hip/hip_bf16.h>

// out[b,q,f] = sum_e ( sum_d g(d) * in[b,q+d,e] ) * M[f,e],   M = Wout @ Win
// g(d) = pdf_N(0,1)(d); |d|<=6 truncation error ~1e-8 << 2% absmax threshold.
// I/O is FLOAT32 (reference dtype); internal U,M are bf16 for MFMA.

typedef unsigned short u16;
typedef unsigned int u32;
typedef unsigned long long u64;
typedef __attribute__((ext_vector_type(8))) short bf16x8;
typedef __attribute__((ext_vector_type(8))) unsigned short u16x8;
typedef __attribute__((ext_vector_type(4))) float f32x4;

typedef __attribute__((address_space(1))) const void* as1_cvp;
typedef __attribute__((address_space(3))) void* as3_vp;

#define EDIM 512
#define SEQ  4096
#define NROW 16384  // B*S = 4*4096

__device__ __forceinline__ u16 f2b(float x) {
  union { float f; u32 u; } c; c.f = x;
  return (u16)((c.u + 0x7fffu + ((c.u >> 16) & 1u)) >> 16);  // RNE
}

// global -> LDS async copy, 16B per lane. LDS dest must be linear in lane order.
__device__ __forceinline__ void async_cp16(const void* g, void* l) {
  __builtin_amdgcn_global_load_lds((as1_cvp)(u64)g, (as3_vp)(u32)(u64)l, 16, 0, 0);
}

// ---------------------------------------------------------------------------
// Kernel 1: M[f,e] = sum_c Wout[f,c] * Win[c,e]   (512x512x512), fp32 in, bf16 out.
// Tile 64x64, BK=32, 4 waves each computing 16 rows x 64 cols.
// ---------------------------------------------------------------------------
__global__ __launch_bounds__(256) void gemm_m(const float* __restrict__ Wout,
                                              const float* __restrict__ Win,
                                              u16* __restrict__ Mm) {
  __shared__ u16 la[64 * 32];   // Wout tile [f][c], bf16
  __shared__ u16 lbt[64 * 32];  // Win^T tile [e][c], bf16
  int t = threadIdx.x;
  int w = t >> 6, l = t & 63, lr = l & 15, lk = l >> 4;
  int f0 = (int)(blockIdx.x >> 3) * 64, e0 = (int)(blockIdx.x & 7) * 64;
  f32x4 acc[4] = {};
  for (int kt = 0; kt < 16; ++kt) {
    int k0 = kt * 32;
    __syncthreads();  // previous iter's reads done before overwrite
    // stage A: 64 rows x 32 cols, 8 fp32 -> 8 bf16 per thread
    {
      const float* src = Wout + (u64)(f0 + (t >> 2)) * EDIM + k0 + (t & 3) * 8;
      u16x8 o;
#pragma unroll
      for (int j = 0; j < 8; ++j) o[j] = f2b(src[j]);
      *(u16x8*)(la + (t >> 2) * 32 + (t & 3) * 8) = o;
    }
    // stage B^T: coalesced fp32 read of Win rows, scalar-scatter transpose
    {
      const float* src = Win + (u64)(k0 + (t >> 3)) * EDIM + e0 + (t & 7) * 8;
#pragma unroll
      for (int j = 0; j < 8; ++j) lbt[((t & 7) * 8 + j) * 32 + (t >> 3)] = f2b(src[j]);
    }
    __syncthreads();
    bf16x8 a = *(const bf16x8*)(la + (w * 16 + lr) * 32 + lk * 8);
#pragma unroll
    for (int ni = 0; ni < 4; ++ni) {
      bf16x8 b = *(const bf16x8*)(lbt + (ni * 16 + lr) * 32 + lk * 8);
      acc[ni] = __builtin_amdgcn_mfma_f32_16x16x32_bf16(a, b, acc[ni], 0, 0, 0);
    }
  }
#pragma unroll
  for (int ni = 0; ni < 4; ++ni)
#pragma unroll
    for (int r = 0; r < 4; ++r)
      Mm[(u64)(f0 + w * 16 + lk * 4 + r) * EDIM + e0 + ni * 16 + lr] = f2b(acc[ni][r]);
}

// ---------------------------------------------------------------------------
// Kernel 2: u[r,e] = sum_{d=-6..6} g(d) * in[r+d, e], zero-padded per batch of 4096.
// fp32 input (no rounding), bf16 output. One thread = 8 channels of one row.
// ---------------------------------------------------------------------------
__global__ __launch_bounds__(256) void conv_g(const float* __restrict__ in,
                                              u16* __restrict__ u) {
  const float G[7] = {0.39894228040143270f, 0.24197072451914337f,
                      0.053990966513188063f, 0.0044318484119380075f,
                      1.3383022576488537e-4f, 1.4867195147342977e-6f,
                      6.0758828498232861e-9f};
  int t = (int)blockIdx.x * 256 + (int)threadIdx.x;  // 16384*64 threads
  int r = t >> 6;
  int c = (t & 63) << 3;
  int s = r & (SEQ - 1);
  const float* base = in + (u64)r * EDIM + c;
  float acc[8] = {0.f, 0.f, 0.f, 0.f, 0.f, 0.f, 0.f, 0.f};
#pragma unroll
  for (int d = -6; d <= 6; ++d) {
    int sp = s + d;
    if ((unsigned)sp < (unsigned)SEQ) {
      f32x4 v0 = *(const f32x4*)(base + (long)d * EDIM);
      f32x4 v1 = *(const f32x4*)(base + (long)d * EDIM + 4);
      float g = G[d < 0 ? -d : d];
#pragma unroll
      for (int j = 0; j < 4; ++j) { acc[j] += g * v0[j]; acc[4 + j] += g * v1[j]; }
    }
  }
  u16x8 o;
#pragma unroll
  for (int j = 0; j < 8; ++j) o[j] = f2b(acc[j]);
  *(u16x8*)(u + (u64)r * EDIM + c) = o;
}

// ---------------------------------------------------------------------------
// Kernel 3: out[r,f] = sum_e u[r,e] * M[f,e].  M=16384, N=512, K=512, fp32 out.
// 128x128 tile, BK=64, 4 waves (2x2), each wave 64x64 = 4x4 frags of 16x16x32.
// global_load_lds width-16 staging, linear LDS [row][64] bf16 (m97 structure).
// ---------------------------------------------------------------------------
__global__ __launch_bounds__(256) void gemm_out(const u16* __restrict__ U,
                                                const u16* __restrict__ Mm,
                                                float* __restrict__ out) {
  __shared__ u16 lds[2 * 128 * 64];  // A tile then B tile, 16KB each
  u16* la = lds;
  u16* lb = lds + 128 * 64;
  int t = threadIdx.x;
  int l = t & 63, lr = l & 15, lk = l >> 4;
  int w = t >> 6, wr = w >> 1, wc = w & 1;
  int m0 = (int)(blockIdx.x >> 2) * 128;
  int n0 = (int)(blockIdx.x & 3) * 128;
  f32x4 acc[4][4] = {};
  const u16* gA = U + (u64)(m0 + (t >> 3)) * EDIM + (t & 7) * 8;
  const u16* gB = Mm + (u64)(n0 + (t >> 3)) * EDIM + (t & 7) * 8;
  u16* sA = la + t * 8;  // 16B per thread, linear in lane order
  u16* sB = lb + t * 8;

  for (int kt = 0; kt < 8; ++kt) {
    int k0 = kt * 64;
#pragma unroll
    for (int i = 0; i < 4; ++i) {  // 32 rows per issue, 4 issues per tile
      async_cp16(gA + (u64)i * 32 * EDIM + k0, sA + i * 2048);
      async_cp16(gB + (u64)i * 32 * EDIM + k0, sB + i * 2048);
    }
    __syncthreads();  // compiler drains vmcnt before barrier
#pragma unroll
    for (int kk = 0; kk < 64; kk += 32) {
      bf16x8 af[4], bfr[4];
#pragma unroll
      for (int mi = 0; mi < 4; ++mi)
        af[mi] = *(const bf16x8*)(la + (wr * 64 + mi * 16 + lr) * 64 + kk + lk * 8);
#pragma unroll
      for (int ni = 0; ni < 4; ++ni)
        bfr[ni] = *(const bf16x8*)(lb + (wc * 64 + ni * 16 + lr) * 64 + kk + lk * 8);
#pragma unroll
      for (int mi = 0; mi < 4; ++mi)
#pragma unroll
        for (int ni = 0; ni < 4; ++ni)
          acc[mi][ni] = __builtin_amdgcn_mfma_f32_16x16x32_bf16(af[mi], bfr[ni],
                                                                acc[mi][ni], 0, 0, 0);
    }
    __syncthreads();
  }
#pragma unroll
  for (int mi = 0; mi < 4; ++mi) {
    int row = m0 + wr * 64 + mi * 16 + lk * 4;
#pragma unroll
    for (int ni = 0; ni < 4; ++ni) {
      int col = n0 + wc * 64 + ni * 16 + lr;
#pragma unroll
      for (int r = 0; r < 4; ++r)
        out[(u64)(row + r) * EDIM + col] = acc[mi][ni][r];
    }
  }
}

extern "C" void kernel_launch(void* const* d_in, const int* in_sizes, int n_in,
                              void* d_out, int out_size, void* d_ws, size_t ws_size,
                              hipStream_t stream) {
  const float* in   = (const float*)d_in[0];  // inputs  [4,4096,512] f32
  const float* Win  = (const float*)d_in[1];  // input_weights [512,512] f32
  const float* Wout = (const float*)d_in[2];  // output_weight [512,512] f32
  float* outp = (float*)d_out;                // [4,4096,512] f32

  // workspace: M (512*512) then U (16384*512), bf16. ~17.3 MB total.
  u16* Mm = (u16*)d_ws;
  u16* U  = (u16*)d_ws + (u64)EDIM * EDIM;

  hipLaunchKernelGGL(conv_g,   dim3(NROW * 64 / 256), dim3(256), 0, stream, in, U);
  hipLaunchKernelGGL(gemm_m,   dim3(64),  dim3(256), 0, stream, Wout, Win, Mm);
  hipLaunchKernelGGL(gemm_out, dim3(512), dim3(256), 0, stream, U, Mm, outp);
}